// Round 5
// baseline (1071.574 us; speedup 1.0000x reference)
//
#include <hip/hip_runtime.h>
#include <hip/hip_bf16.h>
#include <hip/hip_fp16.h>
#include <math.h>

// 2 iterations of {row-L2-normalize -> scatter-add over 32M edges -> 2x2 matmul
// + ReLU}, then sigmoid(x @ final_weight). N = 1M nodes, E = 32M edges.
//
// Pipeline: hist -> colscan -> base -> bin (block-local LDS key sort, coalesced
// flush) -> agg x2 (LDS accumulate per 4096-node dst bucket).
// Partition key = (dst_bucket << SLICE_BITS) | (src >> sliceShift): agg walks
// src slices in order so the random gather slice (1 MB f32 / 0.5 MB half) stays
// resident in each XCD's 4 MB L2 (agg is gather-latency x MLP-capped; lowering
// avg latency is the lever). Iter-1 gathers f32 (sign-critical), iter-2 half2.

#define EPS 1e-15f
#define SB_BITS 12
#define SB 4096              // dst nodes per bucket
#define NBK_MAX 2048
#define CHUNK 8192           // edges per partition block
#define BIN_T 512
#define SCAN_BK 8

typedef unsigned int u32;
typedef unsigned short u16;
typedef unsigned int u32x4 __attribute__((ext_vector_type(4)));

// ---------------- node-wise kernels ----------------

__global__ void norm_input_kernel(const float2* __restrict__ x,
                                  float2* __restrict__ A, int N) {
    int n = blockIdx.x * blockDim.x + threadIdx.x;
    if (n >= N) return;
    float2 v = x[n];
    float nm = sqrtf(v.x * v.x + v.y * v.y);
    float inv = 1.0f / (nm + EPS);
    A[n] = make_float2(v.x * inv, v.y * inv);
}

// iter-1 matmul+relu+normalize, output as half2
__global__ void wrelu_half_kernel(const float2* __restrict__ B,
                                  u32* __restrict__ A1,
                                  const float* __restrict__ W, int N) {
    int n = blockIdx.x * blockDim.x + threadIdx.x;
    if (n >= N) return;
    float w00 = W[0], w01 = W[1], w10 = W[2], w11 = W[3];
    float2 b = B[n];
    float y0 = fmaxf(b.x * w00 + b.y * w10, 0.0f);
    float y1 = fmaxf(b.x * w01 + b.y * w11, 0.0f);
    float nm = sqrtf(y0 * y0 + y1 * y1);
    float inv = 1.0f / (nm + EPS);
    __half2 h = __floats2half2_rn(y0 * inv, y1 * inv);
    A1[n] = __builtin_bit_cast(u32, h);
}

__global__ void wrelu_sig_kernel(const float2* __restrict__ B,
                                 float* __restrict__ out,
                                 const float* __restrict__ W,
                                 const float* __restrict__ fw, int N) {
    int n = blockIdx.x * blockDim.x + threadIdx.x;
    if (n >= N) return;
    float w00 = W[0], w01 = W[1], w10 = W[2], w11 = W[3];
    float f0 = fw[0], f1 = fw[1];
    float2 b = B[n];
    float y0 = fmaxf(b.x * w00 + b.y * w10, 0.0f);
    float y1 = fmaxf(b.x * w01 + b.y * w11, 0.0f);
    float z = y0 * f0 + y1 * f1;
    out[n] = 1.0f / (1.0f + expf(-z));
}

// ---------------- partition pipeline ----------------

// P0: per-(block,key) histogram, block-major H[blk][key]
template <typename HT>
__global__ __launch_bounds__(BIN_T) void hist_k(const int* __restrict__ src,
                                                const int* __restrict__ dst,
                                                int E, int sliceShift,
                                                int sliceBits, int nbk,
                                                HT* __restrict__ H) {
    __shared__ u32 h[NBK_MAX];
    int t = threadIdx.x;
    for (int i = t; i < nbk; i += BIN_T) h[i] = 0;
    __syncthreads();
    int e0 = blockIdx.x * CHUNK, e1 = min(E, e0 + CHUNK);
    for (int e = e0 + t; e < e1; e += BIN_T) {
        int key = ((dst[e] >> SB_BITS) << sliceBits) | (src[e] >> sliceShift);
        atomicAdd(&h[key], 1u);
    }
    __syncthreads();
    HT* row = H + (size_t)blockIdx.x * nbk;
    for (int i = t; i < nbk; i += BIN_T) row[i] = (HT)h[i];
}

// P1: in-place exclusive scan of H along blocks, per key; totals -> T
template <typename HT>
__global__ void colscan_k(HT* __restrict__ H, int gridC, int nbk,
                          u32* __restrict__ T) {
    __shared__ u32 tile[SCAN_BK][257];
    __shared__ u32 carry[SCAN_BK];
    int t = threadIdx.x;                // 256
    int b0 = blockIdx.x * SCAN_BK;
    if (t < SCAN_BK) carry[t] = 0;
    __syncthreads();
    int w = t >> 6, lane = t & 63;
    int rounds = (gridC + 255) / 256;
    for (int i = 0; i < rounds; ++i) {
        int blk = i * 256 + t;
        u32 vals[SCAN_BK];
        #pragma unroll
        for (int j = 0; j < SCAN_BK; ++j) vals[j] = 0;
        if (blk < gridC) {
            const HT* p = H + (size_t)blk * nbk + b0;
            if (sizeof(HT) == 2) {
                uint4 v = *(const uint4*)p;
                vals[0] = v.x & 0xFFFFu; vals[1] = v.x >> 16;
                vals[2] = v.y & 0xFFFFu; vals[3] = v.y >> 16;
                vals[4] = v.z & 0xFFFFu; vals[5] = v.z >> 16;
                vals[6] = v.w & 0xFFFFu; vals[7] = v.w >> 16;
            } else {
                uint4 v0 = ((const uint4*)p)[0], v1 = ((const uint4*)p)[1];
                vals[0] = v0.x; vals[1] = v0.y; vals[2] = v0.z; vals[3] = v0.w;
                vals[4] = v1.x; vals[5] = v1.y; vals[6] = v1.z; vals[7] = v1.w;
            }
        }
        #pragma unroll
        for (int j = 0; j < SCAN_BK; ++j) tile[j][t] = vals[j];
        __syncthreads();
        for (int c = w * 2; c < w * 2 + 2; ++c) {
            u32 cb = carry[c];
            u32 run = 0;
            for (int seg = 0; seg < 4; ++seg) {
                u32 x = tile[c][seg * 64 + lane];
                u32 inc = x;
                for (int off = 1; off < 64; off <<= 1) {
                    u32 y = __shfl_up(inc, off);
                    if (lane >= off) inc += y;
                }
                tile[c][seg * 64 + lane] = inc - x + run + cb;
                run += __shfl(inc, 63);
            }
            if (lane == 0) carry[c] = cb + run;
        }
        __syncthreads();
        if (blk < gridC) {
            #pragma unroll
            for (int j = 0; j < SCAN_BK; ++j) vals[j] = tile[j][t];
            HT* p = H + (size_t)blk * nbk + b0;
            if (sizeof(HT) == 2) {
                uint4 v;
                v.x = vals[0] | (vals[1] << 16);
                v.y = vals[2] | (vals[3] << 16);
                v.z = vals[4] | (vals[5] << 16);
                v.w = vals[6] | (vals[7] << 16);
                *(uint4*)p = v;
            } else {
                uint4 v0 = make_uint4(vals[0], vals[1], vals[2], vals[3]);
                uint4 v1 = make_uint4(vals[4], vals[5], vals[6], vals[7]);
                ((uint4*)p)[0] = v0; ((uint4*)p)[1] = v1;
            }
        }
        __syncthreads();
    }
    if (t < SCAN_BK) T[b0 + t] = carry[t];
}

// P2: key bases, rounded to 4 words (16B) for uint4 agg loads
__global__ __launch_bounds__(512) void base_k(const u32* __restrict__ T,
                                              int nbk, u32* __restrict__ base) {
    __shared__ u32 wp[8];
    int t = threadIdx.x;                // 512
    int VPT = nbk >> 9;                 // 1 or 4
    u32 loc[4];
    u32 s = 0;
    for (int j = 0; j < VPT; ++j) {
        loc[j] = (T[t * VPT + j] + 3u) & ~3u;
        s += loc[j];
    }
    int lane = t & 63, w = t >> 6;
    u32 inc = s;
    for (int off = 1; off < 64; off <<= 1) {
        u32 y = __shfl_up(inc, off);
        if (lane >= off) inc += y;
    }
    if (lane == 63) wp[w] = inc;
    __syncthreads();
    u32 add = 0;
    for (int j = 0; j < w; ++j) add += wp[j];
    u32 run = inc - s + add;
    for (int j = 0; j < VPT; ++j) {
        base[t * VPT + j] = run;
        run += loc[j];
    }
    if (t == 511) base[nbk] = run;
}

// P3: block-local key sort in LDS, then coalesced run flush
template <typename HT>
__global__ __launch_bounds__(BIN_T) void bin_k(const int* __restrict__ src,
                                               const int* __restrict__ dst,
                                               int E, int sliceShift,
                                               int sliceBits, int nbk,
                                               const HT* __restrict__ H,
                                               const u32* __restrict__ base,
                                               u32* __restrict__ bucketed) {
    __shared__ u32 h[NBK_MAX];            // counts, then D = gb - start
    __shared__ u32 cur[NBK_MAX];
    __shared__ u32 stage[CHUNK];          // 32 KB
    __shared__ unsigned char sbk[CHUNK];  // 8 KB (dst bucket)
    __shared__ u32 wp[8];
    int t = threadIdx.x;                  // 512
    int e0 = blockIdx.x * CHUNK, e1 = min(E, e0 + CHUNK), n = e1 - e0;
    for (int i = t; i < nbk; i += BIN_T) h[i] = 0;
    __syncthreads();
    for (int e = e0 + t; e < e1; e += BIN_T) {
        int key = ((dst[e] >> SB_BITS) << sliceBits) | (src[e] >> sliceShift);
        atomicAdd(&h[key], 1u);
    }
    __syncthreads();
    // exclusive scan h -> start; cur = start; D -> h
    int VPT = nbk / BIN_T;                // 1 or 4
    u32 loc[4];
    u32 s = 0;
    for (int j = 0; j < VPT; ++j) {
        loc[j] = h[t * VPT + j];
        s += loc[j];
    }
    int lane = t & 63, w = t >> 6;
    u32 inc = s;
    for (int off = 1; off < 64; off <<= 1) {
        u32 y = __shfl_up(inc, off);
        if (lane >= off) inc += y;
    }
    if (lane == 63) wp[w] = inc;
    __syncthreads();
    u32 add = 0;
    for (int j = 0; j < w; ++j) add += wp[j];
    u32 run = inc - s + add;
    const HT* Hrow = H + (size_t)blockIdx.x * nbk;
    u32 st[4];
    for (int j = 0; j < VPT; ++j) {
        st[j] = run;
        run += loc[j];
    }
    __syncthreads();                       // all counts consumed before h overwrite
    for (int j = 0; j < VPT; ++j) {
        int k = t * VPT + j;
        cur[k] = st[j];
        h[k] = base[k] + (u32)Hrow[k] - st[j];   // D (mod 2^32)
    }
    __syncthreads();
    // rank + stage (key-sorted within block)
    for (int e = e0 + t; e < e1; e += BIN_T) {
        int d = dst[e];
        int sc = src[e];
        int key = ((d >> SB_BITS) << sliceBits) | (sc >> sliceShift);
        u32 r = atomicAdd(&cur[key], 1u);
        stage[r] = ((u32)(d & (SB - 1)) << 20) | (u32)sc;
        sbk[r] = (unsigned char)(d >> SB_BITS);
    }
    __syncthreads();
    // flush: consecutive i -> consecutive global positions within runs
    for (int i = t; i < n; i += BIN_T) {
        u32 wv = stage[i];
        int key = ((int)sbk[i] << sliceBits) | (int)((wv & 0xFFFFFu) >> sliceShift);
        bucketed[h[key] + (u32)i] = wv;
    }
}

// P4: per-dst-bucket aggregation; src slices in order (L2-resident gathers)
template <int MODE>   // 0: f32 float2 table, 1: half2 table
__global__ __launch_bounds__(1024) void agg_k(
        const u32* __restrict__ bucketed,
        const u32* __restrict__ base,
        const u32* __restrict__ T,
        const void* __restrict__ tab,
        float2* __restrict__ B, int N, int NS) {
    __shared__ float acc[SB * 2];         // 32 KB
    int b = blockIdx.x, t = threadIdx.x;  // 1024
    for (int i = t; i < SB * 2; i += 1024) acc[i] = 0.0f;
    __syncthreads();
    const float2* Af = (const float2*)tab;
    const u32* Ah = (const u32*)tab;
    for (int sIdx = 0; sIdx < NS; ++sIdx) {
        int k = b * NS + sIdx;
        u32 p0 = base[k], cnt = T[k];
        for (u32 q = 8u * (u32)t; q < cnt; q += 8192u) {
            const u32x4* p = (const u32x4*)(bucketed + p0 + q);
            u32x4 wa = __builtin_nontemporal_load(p);
            u32x4 wb = __builtin_nontemporal_load(p + 1);
            u32 wv[8] = {wa[0], wa[1], wa[2], wa[3], wb[0], wb[1], wb[2], wb[3]};
            float2 vv[8];
            #pragma unroll
            for (int j = 0; j < 8; ++j) {
                u32 s = wv[j] & 0xFFFFFu;
                s = min(s, (u32)(N - 1));
                if (MODE == 0) {
                    vv[j] = Af[s];
                } else {
                    u32 hw = Ah[s];
                    __half2 h2 = __builtin_bit_cast(__half2, hw);
                    vv[j] = __half22float2(h2);
                }
            }
            #pragma unroll
            for (int j = 0; j < 8; ++j) {
                if (q + j < cnt) {
                    int dl = (int)(wv[j] >> 20);
                    atomicAdd(&acc[2 * dl], vv[j].x);       // ds_add_f32
                    atomicAdd(&acc[2 * dl + 1], vv[j].y);
                }
            }
        }
    }
    __syncthreads();
    int n0 = b << SB_BITS;
    for (int i = t; i < SB && n0 + i < N; i += 1024)
        B[n0 + i] = make_float2(acc[2 * i], acc[2 * i + 1]);
}

// ---------------- fallback: direct global-atomic scatter ----------------

__global__ void wrelu_norm_kernel(const float2* __restrict__ B,
                                  float2* __restrict__ A,
                                  const float* __restrict__ W, int N) {
    int n = blockIdx.x * blockDim.x + threadIdx.x;
    if (n >= N) return;
    float w00 = W[0], w01 = W[1], w10 = W[2], w11 = W[3];
    float2 b = B[n];
    float y0 = fmaxf(b.x * w00 + b.y * w10, 0.0f);
    float y1 = fmaxf(b.x * w01 + b.y * w11, 0.0f);
    float nm = sqrtf(y0 * y0 + y1 * y1);
    float inv = 1.0f / (nm + EPS);
    A[n] = make_float2(y0 * inv, y1 * inv);
}

__global__ void scatter_kernel(const int* __restrict__ src,
                               const int* __restrict__ dst,
                               const float2* __restrict__ A,
                               float* __restrict__ B, int E) {
    int tid = blockIdx.x * blockDim.x + threadIdx.x;
    int stride = gridDim.x * blockDim.x;
    for (int e = tid; e < E; e += stride) {
        int s = src[e];
        int d = dst[e];
        float2 v = A[s];
        atomicAdd(&B[2 * d], v.x);
        atomicAdd(&B[2 * d + 1], v.y);
    }
}

extern "C" void kernel_launch(void* const* d_in, const int* in_sizes, int n_in,
                              void* d_out, int out_size, void* d_ws, size_t ws_size,
                              hipStream_t stream) {
    const float* x = (const float*)d_in[0];          // [N,2]
    const int* edge_index = (const int*)d_in[1];     // [2,E]
    const float* W = (const float*)d_in[2];          // [2,2,2]
    const float* fw = (const float*)d_in[3];         // [2]
    float* out = (float*)d_out;                      // [N]

    const int N = in_sizes[0] / 2;
    const int E = in_sizes[1] / 2;
    const int* src = edge_index;       // row 0 = message source j
    const int* dst = edge_index + E;   // row 1 = aggregation target i

    const int NB = (N + SB - 1) >> SB_BITS;          // 245
    const int gridC = (E + CHUNK - 1) / CHUNK;       // 3907
    int nbits = 1;
    while ((1 << nbits) < N) ++nbits;                // 20 for 1e6

    // workspace: A (f32 table, aliased by half2 table) | U = max(B, H) |
    //            bucketed | T | base
    char* ws = (char*)d_ws;
    float* A0 = (float*)ws;                                  // [N,2] f32
    u32* A1 = (u32*)ws;                                      // [N] half2 alias
    size_t aBytes = (size_t)N * 2 * sizeof(float);
    size_t bBytes = (size_t)N * 2 * sizeof(float);
    size_t h8Bytes = (size_t)gridC * NBK_MAX * sizeof(u16);  // 16 MB
    size_t h2Bytes = (size_t)gridC * 512 * sizeof(u32);      // 8 MB
    size_t u8Bytes = (bBytes > h8Bytes ? bBytes : h8Bytes);
    size_t u2Bytes = (bBytes > h2Bytes ? bBytes : h2Bytes);

    const int BLK = 256;
    const int gridN = (N + BLK - 1) / BLK;

    norm_input_kernel<<<gridN, BLK, 0, stream>>>((const float2*)x, (float2*)A0, N);

    // choose config: 8 slices (u16 H) > 2 slices (u32 H) > atomic fallback
    int mode = 0;
    size_t uBytes = 0;
    {
        size_t tailBytes = ((size_t)E + 8192 + NBK_MAX + NBK_MAX + 2) * sizeof(u32);
        if (ws_size >= aBytes + u8Bytes + tailBytes && NB * 8 <= NBK_MAX &&
            nbits <= 20 && N <= (1 << 20))
            { mode = 8; uBytes = u8Bytes; }
        else if (ws_size >= aBytes + u2Bytes + tailBytes && NB * 2 <= 512 &&
                 nbits <= 20 && N <= (1 << 20))
            { mode = 2; uBytes = u2Bytes; }
    }

    if (mode != 0) {
        float* B = (float*)(ws + aBytes);
        void* Hp = (void*)(ws + aBytes);                     // aliases B
        u32* bucketed = (u32*)(ws + aBytes + uBytes);        // [E + 8192]
        u32* T = bucketed + (size_t)E + 8192;                // [NBK_MAX]
        u32* base = T + NBK_MAX;                             // [NBK_MAX+1]

        int sliceBits = (mode == 8) ? 3 : 1;
        int sliceShift = nbits - sliceBits;
        int nbk = (mode == 8) ? NBK_MAX : 512;

        if (mode == 8) {
            u16* H = (u16*)Hp;
            hist_k<u16><<<gridC, BIN_T, 0, stream>>>(src, dst, E, sliceShift,
                                                     sliceBits, nbk, H);
            colscan_k<u16><<<nbk / SCAN_BK, 256, 0, stream>>>(H, gridC, nbk, T);
            base_k<<<1, 512, 0, stream>>>(T, nbk, base);
            bin_k<u16><<<gridC, BIN_T, 0, stream>>>(src, dst, E, sliceShift,
                                                    sliceBits, nbk, H, base,
                                                    bucketed);
        } else {
            u32* H = (u32*)Hp;
            hist_k<u32><<<gridC, BIN_T, 0, stream>>>(src, dst, E, sliceShift,
                                                     sliceBits, nbk, H);
            colscan_k<u32><<<nbk / SCAN_BK, 256, 0, stream>>>(H, gridC, nbk, T);
            base_k<<<1, 512, 0, stream>>>(T, nbk, base);
            bin_k<u32><<<gridC, BIN_T, 0, stream>>>(src, dst, E, sliceShift,
                                                    sliceBits, nbk, H, base,
                                                    bucketed);
        }
        int NS = (mode == 8) ? 8 : 2;
        // iter 0: gather f32 (sign-critical precision)
        agg_k<0><<<NB, 1024, 0, stream>>>(bucketed, base, T, A0,
                                          (float2*)B, N, NS);
        wrelu_half_kernel<<<gridN, BLK, 0, stream>>>((const float2*)B, A1, W, N);
        // iter 1: gather half2
        agg_k<1><<<NB, 1024, 0, stream>>>(bucketed, base, T, A1,
                                          (float2*)B, N, NS);
        wrelu_sig_kernel<<<gridN, BLK, 0, stream>>>((const float2*)B, out,
                                                    W + 4, fw, N);
    } else {
        // fallback: direct atomic scatter
        float* B = (float*)(ws + aBytes);
        const size_t featBytes = (size_t)N * 2 * sizeof(float);
        const int gridE = 8192;
        hipMemsetAsync(B, 0, featBytes, stream);
        scatter_kernel<<<gridE, BLK, 0, stream>>>(src, dst, (const float2*)A0,
                                                  (float*)B, E);
        wrelu_norm_kernel<<<gridN, BLK, 0, stream>>>((const float2*)B,
                                                     (float2*)A0, W, N);
        hipMemsetAsync(B, 0, featBytes, stream);
        scatter_kernel<<<gridE, BLK, 0, stream>>>(src, dst, (const float2*)A0,
                                                  (float*)B, E);
        wrelu_sig_kernel<<<gridN, BLK, 0, stream>>>((const float2*)B, out,
                                                    W + 4, fw, N);
    }
}

// Round 6
// 601.370 us; speedup vs baseline: 1.7819x; 1.7819x over previous
//
#include <hip/hip_runtime.h>
#include <math.h>

// 2 iterations of {row-L2-normalize -> scatter-add over 32M edges -> 2x2 matmul
// + ReLU}, then sigmoid(x @ final_weight). N = 1M nodes, E = 32M edges.
//
// Key observation (verified ON DEVICE per launch): W's column1 == -column0 for
// both iterations. Then y1 = -y0, and normalize(relu(y)) is EXACTLY (1,0),
// (0,1) or (0,0) by sign(u), u = w00*b0 + w10*b1. The model collapses to
// scalars: iter1 aggregates g[src] (1 f32 LDS atomic/edge, was 2); iter2
// aggregates packed integer class counts (1 u32 LDS atomic/edge, bit-exact).
// agg was pinned at 351us across 3 rounds regardless of cache behavior ->
// LDS-atomic-throughput bound; halving atomics is the lever.
//
// Pipeline: flag -> tables -> hist -> colscan -> base -> bin -> agg1 ->
// (cls | wrelu_norm) -> agg2 -> (final | wrelu_sig). General binned path and
// atomic fallback retained, device-flag gated.

#define EPS 1e-15f
#define SB_BITS 11
#define SB 2048              // dst nodes per bucket (489 blocks ~ 2/CU)
#define NBW 1024             // padded key width (real nbk = 489*2 = 978)
#define CHUNK 16384          // edges per partition block
#define BIN_T 1024
#define SCAN_BK 8

typedef unsigned int u32;
typedef unsigned short u16;
typedef unsigned char u8;
typedef unsigned int u32x4 __attribute__((ext_vector_type(4)));

// ---------------- flag: does W have the col1 == -col0 property? ----------------

__global__ void flag_k(const float* __restrict__ W, u32* __restrict__ flag) {
    bool ok = (W[1] == -W[0]) && (W[3] == -W[2]) &&
              (W[5] == -W[4]) && (W[7] == -W[6]);
    *flag = ok ? 1u : 0u;
}

// ---------------- node-wise kernels ----------------

// spec: g[n] = (w00*x.x + w10*x.y) / (|x| + eps)
__global__ void g_k(const float2* __restrict__ x, const float* __restrict__ W,
                    float* __restrict__ g, int N, const u32* __restrict__ flag) {
    if (*flag != 1u) return;
    int n = blockIdx.x * blockDim.x + threadIdx.x;
    if (n >= N) return;
    float2 v = x[n];
    float nm = sqrtf(v.x * v.x + v.y * v.y);
    float inv = 1.0f / (nm + EPS);
    g[n] = (W[0] * v.x + W[2] * v.y) * inv;
}

// general/fallback: normalize x into A (want: -1 = always, else require *flag==want)
__global__ void norm_input_kernel(const float2* __restrict__ x,
                                  float2* __restrict__ A, int N,
                                  const u32* __restrict__ flag, int want) {
    if (want >= 0 && *flag != (u32)want) return;
    int n = blockIdx.x * blockDim.x + threadIdx.x;
    if (n >= N) return;
    float2 v = x[n];
    float nm = sqrtf(v.x * v.x + v.y * v.y);
    float inv = 1.0f / (nm + EPS);
    A[n] = make_float2(v.x * inv, v.y * inv);
}

// spec: class of u1 -> u8 {0: zero, 1: pos, 2: neg}
__global__ void cls_k(const float* __restrict__ u1, u8* __restrict__ cls, int N,
                      const u32* __restrict__ flag) {
    if (*flag != 1u) return;
    int n = blockIdx.x * blockDim.x + threadIdx.x;
    if (n >= N) return;
    float u = u1[n];
    cls[n] = (u > 0.0f) ? (u8)1 : ((u < 0.0f) ? (u8)2 : (u8)0);
}

// spec: out = sigmoid(f0*relu(u2) + f1*relu(-u2)), u2 = w00'*P + w10'*Q
__global__ void final_s_k(const u32* __restrict__ cnt, float* __restrict__ out,
                          const float* __restrict__ W, const float* __restrict__ fw,
                          int N, const u32* __restrict__ flag) {
    if (*flag != 1u) return;
    int n = blockIdx.x * blockDim.x + threadIdx.x;
    if (n >= N) return;
    u32 c = cnt[n];
    float P = (float)(c >> 16), Q = (float)(c & 0xFFFFu);
    float u2 = W[4] * P + W[6] * Q;
    float z = fw[0] * fmaxf(u2, 0.0f) + fw[1] * fmaxf(-u2, 0.0f);
    out[n] = 1.0f / (1.0f + expf(-z));
}

// general/fallback: A = normalize(relu(B @ W))
__global__ void wrelu_norm_kernel(const float2* __restrict__ B,
                                  float2* __restrict__ A,
                                  const float* __restrict__ W, int N,
                                  const u32* __restrict__ flag, int want) {
    if (want >= 0 && *flag != (u32)want) return;
    int n = blockIdx.x * blockDim.x + threadIdx.x;
    if (n >= N) return;
    float w00 = W[0], w01 = W[1], w10 = W[2], w11 = W[3];
    float2 b = B[n];
    float y0 = fmaxf(b.x * w00 + b.y * w10, 0.0f);
    float y1 = fmaxf(b.x * w01 + b.y * w11, 0.0f);
    float nm = sqrtf(y0 * y0 + y1 * y1);
    float inv = 1.0f / (nm + EPS);
    A[n] = make_float2(y0 * inv, y1 * inv);
}

// general/fallback: out = sigmoid(relu(B @ W) . fw)
__global__ void wrelu_sig_kernel(const float2* __restrict__ B,
                                 float* __restrict__ out,
                                 const float* __restrict__ W,
                                 const float* __restrict__ fw, int N,
                                 const u32* __restrict__ flag, int want) {
    if (want >= 0 && *flag != (u32)want) return;
    int n = blockIdx.x * blockDim.x + threadIdx.x;
    if (n >= N) return;
    float w00 = W[0], w01 = W[1], w10 = W[2], w11 = W[3];
    float f0 = fw[0], f1 = fw[1];
    float2 b = B[n];
    float y0 = fmaxf(b.x * w00 + b.y * w10, 0.0f);
    float y1 = fmaxf(b.x * w01 + b.y * w11, 0.0f);
    float z = y0 * f0 + y1 * f1;
    out[n] = 1.0f / (1.0f + expf(-z));
}

// ---------------- partition pipeline (flag-independent) ----------------

// P0: per-(block,key) histogram, block-major H[blk][key]; key = bucket*2 | slice
__global__ __launch_bounds__(BIN_T) void hist_k(const int* __restrict__ src,
                                                const int* __restrict__ dst,
                                                int E, int sliceShift,
                                                u16* __restrict__ H) {
    __shared__ u32 h[NBW];
    int t = threadIdx.x;
    for (int i = t; i < NBW; i += BIN_T) h[i] = 0;
    __syncthreads();
    int e0 = blockIdx.x * CHUNK, e1 = min(E, e0 + CHUNK);
    for (int e = e0 + t; e < e1; e += BIN_T) {
        int key = ((dst[e] >> SB_BITS) << 1) | (src[e] >> sliceShift);
        atomicAdd(&h[key], 1u);
    }
    __syncthreads();
    u16* row = H + (size_t)blockIdx.x * NBW;
    for (int i = t; i < NBW; i += BIN_T) row[i] = (u16)h[i];
}

// P1: in-place exclusive scan of H along blocks, per key; totals -> T
__global__ void colscan_k(u16* __restrict__ H, int gridC, u32* __restrict__ T) {
    __shared__ u32 tile[SCAN_BK][257];
    __shared__ u32 carry[SCAN_BK];
    int t = threadIdx.x;                // 256
    int b0 = blockIdx.x * SCAN_BK;
    if (t < SCAN_BK) carry[t] = 0;
    __syncthreads();
    int w = t >> 6, lane = t & 63;
    int rounds = (gridC + 255) / 256;
    for (int i = 0; i < rounds; ++i) {
        int blk = i * 256 + t;
        u32 vals[SCAN_BK];
        #pragma unroll
        for (int j = 0; j < SCAN_BK; ++j) vals[j] = 0;
        if (blk < gridC) {
            const u16* p = H + (size_t)blk * NBW + b0;
            uint4 v = *(const uint4*)p;     // 8 x u16
            vals[0] = v.x & 0xFFFFu; vals[1] = v.x >> 16;
            vals[2] = v.y & 0xFFFFu; vals[3] = v.y >> 16;
            vals[4] = v.z & 0xFFFFu; vals[5] = v.z >> 16;
            vals[6] = v.w & 0xFFFFu; vals[7] = v.w >> 16;
        }
        #pragma unroll
        for (int j = 0; j < SCAN_BK; ++j) tile[j][t] = vals[j];
        __syncthreads();
        for (int c = w * 2; c < w * 2 + 2; ++c) {
            u32 cb = carry[c];
            u32 run = 0;
            for (int seg = 0; seg < 4; ++seg) {
                u32 x = tile[c][seg * 64 + lane];
                u32 inc = x;
                for (int off = 1; off < 64; off <<= 1) {
                    u32 y = __shfl_up(inc, off);
                    if (lane >= off) inc += y;
                }
                tile[c][seg * 64 + lane] = inc - x + run + cb;
                run += __shfl(inc, 63);
            }
            if (lane == 0) carry[c] = cb + run;
        }
        __syncthreads();
        if (blk < gridC) {
            #pragma unroll
            for (int j = 0; j < SCAN_BK; ++j) vals[j] = tile[j][t];
            u16* p = H + (size_t)blk * NBW + b0;
            uint4 v;
            v.x = vals[0] | (vals[1] << 16);
            v.y = vals[2] | (vals[3] << 16);
            v.z = vals[4] | (vals[5] << 16);
            v.w = vals[6] | (vals[7] << 16);
            *(uint4*)p = v;
        }
        __syncthreads();
    }
    if (t < SCAN_BK) T[b0 + t] = carry[t];
}

// P2: key bases, rounded to 4 words (16B) for uint4 agg loads
__global__ __launch_bounds__(512) void base_k(const u32* __restrict__ T,
                                              u32* __restrict__ base) {
    __shared__ u32 wp[8];
    int t = threadIdx.x;                // 512, VPT = 2
    u32 loc[2];
    u32 s = 0;
    for (int j = 0; j < 2; ++j) {
        loc[j] = (T[t * 2 + j] + 3u) & ~3u;
        s += loc[j];
    }
    int lane = t & 63, w = t >> 6;
    u32 inc = s;
    for (int off = 1; off < 64; off <<= 1) {
        u32 y = __shfl_up(inc, off);
        if (lane >= off) inc += y;
    }
    if (lane == 63) wp[w] = inc;
    __syncthreads();
    u32 add = 0;
    for (int j = 0; j < w; ++j) add += wp[j];
    u32 run = inc - s + add;
    for (int j = 0; j < 2; ++j) {
        base[t * 2 + j] = run;
        run += loc[j];
    }
    if (t == 511) base[NBW] = run;
}

// P3: block-local key sort in LDS, then coalesced run flush
__global__ __launch_bounds__(BIN_T) void bin_k(const int* __restrict__ src,
                                               const int* __restrict__ dst,
                                               int E, int sliceShift,
                                               const u16* __restrict__ H,
                                               const u32* __restrict__ base,
                                               u32* __restrict__ bucketed) {
    __shared__ u32 h[NBW];               // counts, then D = base + Hrow - start
    __shared__ u32 cur[NBW];
    __shared__ u32 stage[CHUNK];         // 64 KB
    __shared__ u16 kk[CHUNK];            // 32 KB
    __shared__ u32 wp[16];
    int t = threadIdx.x;                 // 1024
    int e0 = blockIdx.x * CHUNK, e1 = min(E, e0 + CHUNK), n = e1 - e0;
    h[t] = 0;
    __syncthreads();
    for (int e = e0 + t; e < e1; e += BIN_T) {
        int key = ((dst[e] >> SB_BITS) << 1) | (src[e] >> sliceShift);
        atomicAdd(&h[key], 1u);
    }
    __syncthreads();
    // exclusive scan h -> start (1 key per thread)
    u32 v = h[t];
    int lane = t & 63, w = t >> 6;
    u32 inc = v;
    for (int off = 1; off < 64; off <<= 1) {
        u32 y = __shfl_up(inc, off);
        if (lane >= off) inc += y;
    }
    if (lane == 63) wp[w] = inc;
    __syncthreads();
    u32 add = 0;
    for (int j = 0; j < w; ++j) add += wp[j];
    u32 start = inc - v + add;
    cur[t] = start;
    h[t] = base[t] + (u32)H[(size_t)blockIdx.x * NBW + t] - start;  // D (mod 2^32)
    __syncthreads();
    // rank + stage (key-sorted within block)
    for (int e = e0 + t; e < e1; e += BIN_T) {
        int d = dst[e];
        int sc = src[e];
        int key = ((d >> SB_BITS) << 1) | (sc >> sliceShift);
        u32 r = atomicAdd(&cur[key], 1u);
        stage[r] = ((u32)(d & (SB - 1)) << 20) | (u32)sc;
        kk[r] = (u16)key;
    }
    __syncthreads();
    // flush: consecutive i -> consecutive global positions within runs
    for (int i = t; i < n; i += BIN_T)
        bucketed[h[kk[i]] + (u32)i] = stage[i];
}

// ---------------- aggregation ----------------

// spec: KIND 0 = f32 g-table -> u1 (1 f32 LDS atomic/edge)
//       KIND 1 = u8 class table -> packed P<<16|Q counts (1 u32 LDS atomic/edge)
template <int KIND>
__global__ __launch_bounds__(1024) void agg_s(
        const u32* __restrict__ bucketed, const u32* __restrict__ base,
        const u32* __restrict__ T, const void* __restrict__ tab,
        u32* __restrict__ outp, int N, const u32* __restrict__ flag) {
    if (*flag != 1u) return;
    __shared__ u32 acc[SB];              // 8 KB
    int b = blockIdx.x, t = threadIdx.x;
    for (int i = t; i < SB; i += 1024) acc[i] = 0u;
    __syncthreads();
    const float* gt = (const float*)tab;
    const u8* ct = (const u8*)tab;
    #pragma unroll
    for (int sl = 0; sl < 2; ++sl) {
        int k = b * 2 + sl;
        u32 p0 = base[k], cnt = T[k];
        for (u32 q = 8u * (u32)t; q < cnt; q += 8192u) {
            const u32x4* p = (const u32x4*)(bucketed + p0 + q);
            u32x4 wa = __builtin_nontemporal_load(p);
            u32x4 wb = __builtin_nontemporal_load(p + 1);
            u32 wv[8] = {wa[0], wa[1], wa[2], wa[3], wb[0], wb[1], wb[2], wb[3]};
            if (KIND == 0) {
                float gv[8];
                #pragma unroll
                for (int j = 0; j < 8; ++j) {
                    u32 s = wv[j] & 0xFFFFFu;
                    s = min(s, (u32)(N - 1));
                    gv[j] = gt[s];
                }
                #pragma unroll
                for (int j = 0; j < 8; ++j)
                    if (q + j < cnt)
                        atomicAdd((float*)&acc[wv[j] >> 20], gv[j]);
            } else {
                u32 av[8];
                #pragma unroll
                for (int j = 0; j < 8; ++j) {
                    u32 s = wv[j] & 0xFFFFFu;
                    s = min(s, (u32)(N - 1));
                    u8 c = ct[s];
                    av[j] = (c == (u8)1) ? 65536u : ((c == (u8)2) ? 1u : 0u);
                }
                #pragma unroll
                for (int j = 0; j < 8; ++j)
                    if (q + j < cnt)
                        atomicAdd(&acc[wv[j] >> 20], av[j]);
            }
        }
    }
    __syncthreads();
    int n0 = b << SB_BITS;
    for (int i = t; i < SB && n0 + i < N; i += 1024) outp[n0 + i] = acc[i];
}

// general: float2 table -> float2 B (2 f32 LDS atomics/edge)
__global__ __launch_bounds__(1024) void agg_g(
        const u32* __restrict__ bucketed, const u32* __restrict__ base,
        const u32* __restrict__ T, const float2* __restrict__ A,
        float2* __restrict__ B, int N, const u32* __restrict__ flag) {
    if (*flag != 0u) return;
    __shared__ float acc[SB * 2];        // 16 KB
    int b = blockIdx.x, t = threadIdx.x;
    for (int i = t; i < SB * 2; i += 1024) acc[i] = 0.0f;
    __syncthreads();
    #pragma unroll
    for (int sl = 0; sl < 2; ++sl) {
        int k = b * 2 + sl;
        u32 p0 = base[k], cnt = T[k];
        for (u32 q = 8u * (u32)t; q < cnt; q += 8192u) {
            const u32x4* p = (const u32x4*)(bucketed + p0 + q);
            u32x4 wa = __builtin_nontemporal_load(p);
            u32x4 wb = __builtin_nontemporal_load(p + 1);
            u32 wv[8] = {wa[0], wa[1], wa[2], wa[3], wb[0], wb[1], wb[2], wb[3]};
            float2 vv[8];
            #pragma unroll
            for (int j = 0; j < 8; ++j) {
                u32 s = wv[j] & 0xFFFFFu;
                s = min(s, (u32)(N - 1));
                vv[j] = A[s];
            }
            #pragma unroll
            for (int j = 0; j < 8; ++j) {
                if (q + j < cnt) {
                    int dl = (int)(wv[j] >> 20);
                    atomicAdd(&acc[2 * dl], vv[j].x);
                    atomicAdd(&acc[2 * dl + 1], vv[j].y);
                }
            }
        }
    }
    __syncthreads();
    int n0 = b << SB_BITS;
    for (int i = t; i < SB && n0 + i < N; i += 1024)
        B[n0 + i] = make_float2(acc[2 * i], acc[2 * i + 1]);
}

// ---------------- fallback: direct global-atomic scatter ----------------

__global__ void scatter_kernel(const int* __restrict__ src,
                               const int* __restrict__ dst,
                               const float2* __restrict__ A,
                               float* __restrict__ B, int E) {
    int tid = blockIdx.x * blockDim.x + threadIdx.x;
    int stride = gridDim.x * blockDim.x;
    for (int e = tid; e < E; e += stride) {
        int s = src[e];
        int d = dst[e];
        float2 v = A[s];
        atomicAdd(&B[2 * d], v.x);
        atomicAdd(&B[2 * d + 1], v.y);
    }
}

extern "C" void kernel_launch(void* const* d_in, const int* in_sizes, int n_in,
                              void* d_out, int out_size, void* d_ws, size_t ws_size,
                              hipStream_t stream) {
    const float* x = (const float*)d_in[0];          // [N,2]
    const int* edge_index = (const int*)d_in[1];     // [2,E]
    const float* W = (const float*)d_in[2];          // [2,2,2]
    const float* fw = (const float*)d_in[3];         // [2]
    float* out = (float*)d_out;                      // [N]

    const int N = in_sizes[0] / 2;
    const int E = in_sizes[1] / 2;
    const int* src = edge_index;       // row 0 = message source j
    const int* dst = edge_index + E;   // row 1 = aggregation target i

    const int NB = (N + SB - 1) >> SB_BITS;          // 489
    const int gridC = (E + CHUNK - 1) / CHUNK;       // 1954
    int nbits = 1;
    while ((1 << nbits) < N) ++nbits;                // 20
    const int sliceShift = nbits - 1;                // 2 src slices

    // workspace layout:
    //  U1 [0, 8MB): spec: g f32[N] @0, cls u8[N] @4MB | general: A0 float2[N]
    //  U2 [8MB, +max(H, B, u1+cnt)): H u16[gridC*NBW] (dead before agg writes)
    //        spec: u1 f32[N] @+0, cnt u32[N] @+4MB | general: B float2[N]
    //  bucketed u32[E + CHUNK] | T u32[NBW] | base u32[NBW+1] | flag u32
    char* ws = (char*)d_ws;
    size_t aBytes = (size_t)N * 2 * sizeof(float);           // 8 MB
    size_t hBytes = (size_t)gridC * NBW * sizeof(u16);       // ~4 MB
    size_t bBytes = (size_t)N * 2 * sizeof(float);           // 8 MB
    size_t uBytes = (hBytes > bBytes ? hBytes : bBytes);

    float* g    = (float*)ws;
    u8*   cls   = (u8*)(ws + (size_t)N * sizeof(float));
    float2* A0  = (float2*)ws;
    u16*  H     = (u16*)(ws + aBytes);
    float* u1   = (float*)(ws + aBytes);
    u32*  cnt   = (u32*)(ws + aBytes + (size_t)N * sizeof(float));
    float* Bg   = (float*)(ws + aBytes);
    u32* bucketed = (u32*)(ws + aBytes + uBytes);            // [E + CHUNK]
    u32* T    = bucketed + (size_t)E + CHUNK;                // [NBW]
    u32* base = T + NBW;                                     // [NBW+1]
    u32* flag = base + NBW + 1;
    size_t need = (char*)(flag + 1) - ws;

    const int BLK = 256;
    const int gridN = (N + BLK - 1) / BLK;

    flag_k<<<1, 1, 0, stream>>>(W, flag);

    if (ws_size >= need && 2 * NB <= NBW && N <= (1 << 20) && E <= (1 << 25)) {
        // tables (flag-gated; disjoint use of U1)
        g_k<<<gridN, BLK, 0, stream>>>((const float2*)x, W, g, N, flag);
        norm_input_kernel<<<gridN, BLK, 0, stream>>>((const float2*)x, A0, N,
                                                     flag, 0);
        // partition (flag-independent)
        hist_k<<<gridC, BIN_T, 0, stream>>>(src, dst, E, sliceShift, H);
        colscan_k<<<NBW / SCAN_BK, 256, 0, stream>>>(H, gridC, T);
        base_k<<<1, 512, 0, stream>>>(T, base);
        bin_k<<<gridC, BIN_T, 0, stream>>>(src, dst, E, sliceShift, H, base,
                                           bucketed);
        // iter 1
        agg_s<0><<<NB, 1024, 0, stream>>>(bucketed, base, T, g, (u32*)u1, N, flag);
        agg_g<<<NB, 1024, 0, stream>>>(bucketed, base, T, (const float2*)A0,
                                       (float2*)Bg, N, flag);
        cls_k<<<gridN, BLK, 0, stream>>>(u1, cls, N, flag);
        wrelu_norm_kernel<<<gridN, BLK, 0, stream>>>((const float2*)Bg, A0, W,
                                                     N, flag, 0);
        // iter 2
        agg_s<1><<<NB, 1024, 0, stream>>>(bucketed, base, T, cls, cnt, N, flag);
        agg_g<<<NB, 1024, 0, stream>>>(bucketed, base, T, (const float2*)A0,
                                       (float2*)Bg, N, flag);
        final_s_k<<<gridN, BLK, 0, stream>>>(cnt, out, W, fw, N, flag);
        wrelu_sig_kernel<<<gridN, BLK, 0, stream>>>((const float2*)Bg, out,
                                                    W + 4, fw, N, flag, 0);
    } else {
        // fallback: direct atomic scatter (generic, flag-independent)
        float* B = (float*)(ws + aBytes);
        const size_t featBytes = (size_t)N * 2 * sizeof(float);
        const int gridE = 8192;
        norm_input_kernel<<<gridN, BLK, 0, stream>>>((const float2*)x, A0, N,
                                                     flag, -1);
        hipMemsetAsync(B, 0, featBytes, stream);
        scatter_kernel<<<gridE, BLK, 0, stream>>>(src, dst, (const float2*)A0,
                                                  B, E);
        wrelu_norm_kernel<<<gridN, BLK, 0, stream>>>((const float2*)B, A0, W,
                                                     N, flag, -1);
        hipMemsetAsync(B, 0, featBytes, stream);
        scatter_kernel<<<gridE, BLK, 0, stream>>>(src, dst, (const float2*)A0,
                                                  B, E);
        wrelu_sig_kernel<<<gridN, BLK, 0, stream>>>((const float2*)B, out,
                                                    W + 4, fw, N, flag, -1);
    }
}